// Round 1
// baseline (610.561 us; speedup 1.0000x reference)
//
#include <hip/hip_runtime.h>
#include <hip/hip_bf16.h>

// Problem constants (from reference):
//   z: (8,2048,64) f32  -> N=16384, D=64
//   codebook: (8192,64) f32 -> K=8192
//   ema_cluster_size: (8192,) f32
//   ema_weight_sum: (8192,64) f32
// Outputs concat (f32): z_q_st[1048576], vq_loss[1], idx[16384],
//   new_codebook[524288], new_cs[8192], new_ws[524288]  -> 2121729 total

#define NQ 16384
#define KC 8192
#define DD 64
#define KSPLIT 16            // code chunks for argmin kernel
#define CHUNK (KC / KSPLIT)  // 512 codes per block

// ---------------- workspace layout (floats) ----------------
// [0)        dw accumulator      524288
// [524288)   cluster_size acc    8192
// [532480)   sumsq               1
// [532481)   n accumulator       1
// [532484)   cnorm               8192
// [540676)   pmin                16384*16 = 262144
// [802820)   pidx (int)          262144
// [1064964)  idx (int)           16384
// total 1081348 floats = 4.33 MB

__global__ __launch_bounds__(256) void k_cnorm(const float* __restrict__ cb,
                                               float* __restrict__ cnorm) {
  int k = blockIdx.x * 256 + threadIdx.x;
  const float* __restrict__ r = cb + (size_t)k * DD;
  float a0 = 0.f, a1 = 0.f, a2 = 0.f, a3 = 0.f;
#pragma unroll
  for (int d = 0; d < DD; d += 4) {
    a0 = fmaf(r[d], r[d], a0);
    a1 = fmaf(r[d + 1], r[d + 1], a1);
    a2 = fmaf(r[d + 2], r[d + 2], a2);
    a3 = fmaf(r[d + 3], r[d + 3], a3);
  }
  cnorm[k] = (a0 + a1) + (a2 + a3);
}

// Fused distance + partial argmin. lane = query (query held in VGPRs),
// code index is wave-uniform -> codebook row reads become scalar loads.
__global__ __launch_bounds__(256) void k_argmin(
    const float* __restrict__ z, const float* __restrict__ cb,
    const float* __restrict__ cnorm, float* __restrict__ pmin,
    int* __restrict__ pidx) {
  const int q = blockIdx.x * 256 + threadIdx.x;  // 0..16383
  const int ks = blockIdx.y;                     // 0..KSPLIT-1

  float zr[DD];
#pragma unroll
  for (int d = 0; d < DD; d += 4) {
    const float4 v = *(const float4*)(z + (size_t)q * DD + d);
    zr[d] = v.x; zr[d + 1] = v.y; zr[d + 2] = v.z; zr[d + 3] = v.w;
  }
  float x0 = 0.f, x1 = 0.f, x2 = 0.f, x3 = 0.f;
#pragma unroll
  for (int d = 0; d < DD; d += 4) {
    x0 = fmaf(zr[d], zr[d], x0);
    x1 = fmaf(zr[d + 1], zr[d + 1], x1);
    x2 = fmaf(zr[d + 2], zr[d + 2], x2);
    x3 = fmaf(zr[d + 3], zr[d + 3], x3);
  }
  const float xnorm = (x0 + x1) + (x2 + x3);

  float best = 3.4e38f;
  int bi = 0;
  const int c0 = ks * CHUNK;
  for (int c = c0; c < c0 + CHUNK; ++c) {
    const float* __restrict__ crow = cb + (size_t)c * DD;  // wave-uniform
    float a0 = 0.f, a1 = 0.f, a2 = 0.f, a3 = 0.f;
#pragma unroll
    for (int d = 0; d < DD; d += 4) {
      a0 = fmaf(crow[d], zr[d], a0);
      a1 = fmaf(crow[d + 1], zr[d + 1], a1);
      a2 = fmaf(crow[d + 2], zr[d + 2], a2);
      a3 = fmaf(crow[d + 3], zr[d + 3], a3);
    }
    const float dot = (a0 + a1) + (a2 + a3);
    // Match reference rounding order: (||x||^2 - 2*dot) + ||c||^2
    const float dist = (xnorm - 2.0f * dot) + cnorm[c];
    if (dist < best) { best = dist; bi = c; }
  }
  pmin[(size_t)ks * NQ + q] = best;
  pidx[(size_t)ks * NQ + q] = bi;
}

__global__ __launch_bounds__(256) void k_finalize(
    const float* __restrict__ pmin, const int* __restrict__ pidx,
    int* __restrict__ idx_i, float* __restrict__ out_idx) {
  int q = blockIdx.x * 256 + threadIdx.x;
  float best = pmin[q];
  int bi = pidx[q];
#pragma unroll
  for (int s = 1; s < KSPLIT; ++s) {
    float v = pmin[(size_t)s * NQ + q];
    int i = pidx[(size_t)s * NQ + q];
    if (v < best || (v == best && i < bi)) { best = v; bi = i; }
  }
  idx_i[q] = bi;
  out_idx[q] = (float)bi;  // harness reads d_out as f32; idx<8192 exact
}

// One wave per query: gather z_q, loss partial, scatter count + dw.
__global__ __launch_bounds__(256) void k_gather_scatter(
    const float* __restrict__ z, const float* __restrict__ cb,
    const int* __restrict__ idx_i, float* __restrict__ out_zq,
    float* __restrict__ dw, float* __restrict__ cs,
    float* __restrict__ sumsq) {
  int t = blockIdx.x * 256 + threadIdx.x;
  int q = t >> 6;
  int d = t & 63;
  int k = idx_i[q];
  float zv = z[t];
  float cv = cb[(size_t)k * DD + d];
  out_zq[t] = cv;  // z + (z_q - z) == z_q
  float diff = zv - cv;
  float sq = diff * diff;
#pragma unroll
  for (int off = 32; off > 0; off >>= 1) sq += __shfl_down(sq, off, 64);
  if (d == 0) {
    atomicAdd(sumsq, sq);
    atomicAdd(&cs[k], 1.0f);
  }
  atomicAdd(&dw[(size_t)k * DD + d], zv);
}

__global__ __launch_bounds__(256) void k_newcs(
    const float* __restrict__ ema_cs, const float* __restrict__ cs,
    float* __restrict__ out_ncs, float* __restrict__ n_acc) {
  int k = blockIdx.x * 256 + threadIdx.x;
  float v = 0.99f * ema_cs[k] + 0.01f * cs[k];
  out_ncs[k] = v;
  float s = v;
#pragma unroll
  for (int off = 32; off > 0; off >>= 1) s += __shfl_down(s, off, 64);
  __shared__ float ss[4];
  if ((threadIdx.x & 63) == 0) ss[threadIdx.x >> 6] = s;
  __syncthreads();
  if (threadIdx.x == 0) atomicAdd(n_acc, ss[0] + ss[1] + ss[2] + ss[3]);
}

__global__ __launch_bounds__(256) void k_finalout(
    const float* __restrict__ ema_ws, const float* __restrict__ dw,
    const float* __restrict__ ncs, const float* __restrict__ n_acc,
    const float* __restrict__ sumsq, float* __restrict__ out_ncb,
    float* __restrict__ out_nws, float* __restrict__ out_loss) {
  int i = blockIdx.x * 256 + threadIdx.x;
  int k = i >> 6;
  float n = *n_acc;
  float v = ncs[k];
  float smoothed = (v + 1e-5f) / (n + (float)KC * 1e-5f) * n;
  float nws = 0.99f * ema_ws[i] + 0.01f * dw[i];
  out_nws[i] = nws;
  out_ncb[i] = nws / smoothed;
  if (i == 0) *out_loss = 1.25f * (*sumsq) * (1.0f / 1048576.0f);
}

extern "C" void kernel_launch(void* const* d_in, const int* in_sizes, int n_in,
                              void* d_out, int out_size, void* d_ws,
                              size_t ws_size, hipStream_t stream) {
  const float* z = (const float*)d_in[0];
  const float* cb = (const float*)d_in[1];
  const float* ema_cs = (const float*)d_in[2];
  const float* ema_ws = (const float*)d_in[3];

  float* out = (float*)d_out;
  float* zq_out = out;                 // 1048576
  float* loss_out = out + 1048576;     // 1
  float* idx_out = out + 1048577;      // 16384
  float* ncb_out = out + 1064961;      // 524288
  float* ncs_out = out + 1589249;      // 8192
  float* nws_out = out + 1597441;      // 524288

  float* ws = (float*)d_ws;
  float* dw = ws;                      // 524288
  float* cs = ws + 524288;             // 8192
  float* sumsq = ws + 532480;          // 1
  float* n_acc = ws + 532481;          // 1
  float* cnorm = ws + 532484;          // 8192
  float* pmin = ws + 540676;           // 262144
  int* pidx = (int*)(ws + 802820);     // 262144
  int* idx_i = (int*)(ws + 1064964);   // 16384

  // Zero accumulators (dw, cs, sumsq, n_acc are contiguous)
  hipMemsetAsync(d_ws, 0, (size_t)532482 * sizeof(float), stream);

  k_cnorm<<<KC / 256, 256, 0, stream>>>(cb, cnorm);
  k_argmin<<<dim3(NQ / 256, KSPLIT), 256, 0, stream>>>(z, cb, cnorm, pmin,
                                                       pidx);
  k_finalize<<<NQ / 256, 256, 0, stream>>>(pmin, pidx, idx_i, idx_out);
  k_gather_scatter<<<NQ * DD / 256, 256, 0, stream>>>(z, cb, idx_i, zq_out, dw,
                                                      cs, sumsq);
  k_newcs<<<KC / 256, 256, 0, stream>>>(ema_cs, cs, ncs_out, n_acc);
  k_finalout<<<KC * DD / 256, 256, 0, stream>>>(ema_ws, dw, ncs_out, n_acc,
                                                sumsq, ncb_out, nws_out,
                                                loss_out);
}

// Round 2
// 437.862 us; speedup vs baseline: 1.3944x; 1.3944x over previous
//
#include <hip/hip_runtime.h>
#include <hip/hip_bf16.h>

// z: (8,2048,64) f32 -> N=16384, D=64 ; codebook: (8192,64) f32
// outputs (f32, concat): z_q_st[1048576], vq_loss[1], idx[16384],
//   new_codebook[524288], new_cs[8192], new_ws[524288]

#define NQ 16384
#define KC 8192
#define DD 64
#define KSPLIT 16
#define CHUNK (KC / KSPLIT)

using f4 = __attribute__((ext_vector_type(4))) float;
using f2 = __attribute__((ext_vector_type(2))) float;

#define R16(M) M(0) M(1) M(2) M(3) M(4) M(5) M(6) M(7) \
               M(8) M(9) M(10) M(11) M(12) M(13) M(14) M(15)

// ---------------- workspace layout (floats) ----------------
// [0)        dw          524288
// [524288)   cs          8192
// [532480)   parts       64      (sumsq spread buckets)
// [532544)   n_acc       1
// [532545)   sumsq_tot   1
// [532608)   cnorm       8192
// [540800)   pmin        262144
// [802944)   pidx (int)  262144

__global__ __launch_bounds__(256) void k_cnorm(const float* __restrict__ cb,
                                               float* __restrict__ cnorm) {
  int k = blockIdx.x * 256 + threadIdx.x;
  const float* __restrict__ r = cb + (size_t)k * DD;
  float a0 = 0.f, a1 = 0.f, a2 = 0.f, a3 = 0.f;
#pragma unroll
  for (int d = 0; d < DD; d += 4) {
    a0 = fmaf(r[d], r[d], a0);
    a1 = fmaf(r[d + 1], r[d + 1], a1);
    a2 = fmaf(r[d + 2], r[d + 2], a2);
    a3 = fmaf(r[d + 3], r[d + 3], a3);
  }
  cnorm[k] = (a0 + a1) + (a2 + a3);
}

// lane = query; z row pinned in 16 named f4 registers; code index is
// wave-uniform -> codebook row reads lower to s_load; dot via packed f2 FMA
// with the SAME accumulator split (d mod 4) and tree-sum as the passing R1
// kernel -> bit-identical distances.
__global__ __launch_bounds__(256) void k_argmin(
    const float* __restrict__ z, const float* __restrict__ cb,
    const float* __restrict__ cnorm, float* __restrict__ pmin,
    int* __restrict__ pidx) {
  const int q = blockIdx.x * 256 + threadIdx.x;
  const int ks = blockIdx.y;

  const f4* __restrict__ zp = (const f4*)(z + (size_t)q * DD);
#define LZ(i) const f4 z##i = zp[i];
  R16(LZ)
#undef LZ

  f2 XA = {0.f, 0.f}, XB = {0.f, 0.f};
#define XS(i)                                            \
  XA = __builtin_elementwise_fma(z##i.lo, z##i.lo, XA);  \
  XB = __builtin_elementwise_fma(z##i.hi, z##i.hi, XB);
  R16(XS)
#undef XS
  const float xnorm = (XA.x + XA.y) + (XB.x + XB.y);

  float best = 3.4e38f;
  int bi = 0;
  const int c0 = ks * CHUNK;
  for (int c = c0; c < c0 + CHUNK; ++c) {
    const f4* __restrict__ cp = (const f4*)(cb + (size_t)c * DD);
    f2 A = {0.f, 0.f}, B = {0.f, 0.f};
#define DS(i)                                       \
  {                                                 \
    const f4 cc = cp[i];                            \
    A = __builtin_elementwise_fma(cc.lo, z##i.lo, A); \
    B = __builtin_elementwise_fma(cc.hi, z##i.hi, B); \
  }
    R16(DS)
#undef DS
    const float dot = (A.x + A.y) + (B.x + B.y);
    const float dist = (xnorm - 2.0f * dot) + cnorm[c];
    if (dist < best) { best = dist; bi = c; }
  }
  pmin[(size_t)ks * NQ + q] = best;
  pidx[(size_t)ks * NQ + q] = bi;
}

// Fused: per-query 16-way argmin merge (shuffle), z_q gather, idx write,
// loss partial (spread buckets), cs/dw scatter. One wave per query.
__global__ __launch_bounds__(256) void k_assign(
    const float* __restrict__ z, const float* __restrict__ cb,
    const float* __restrict__ pmin, const int* __restrict__ pidx,
    float* __restrict__ out_zq, float* __restrict__ out_idx,
    float* __restrict__ dw, float* __restrict__ cs,
    float* __restrict__ parts) {
  const int t = threadIdx.x;
  const int d = t & 63;
  const int q = blockIdx.x * 4 + (t >> 6);

  const int s = d & 15;
  float v = pmin[(size_t)s * NQ + q];
  int i = pidx[(size_t)s * NQ + q];
#pragma unroll
  for (int off = 1; off < 16; off <<= 1) {
    float v2 = __shfl_xor(v, off, 64);
    int i2 = __shfl_xor(i, off, 64);
    if (v2 < v || (v2 == v && i2 < i)) { v = v2; i = i2; }
  }
  const int k = i;  // all lanes agree

  const float zv = z[(size_t)q * DD + d];
  const float cv = cb[(size_t)k * DD + d];
  out_zq[(size_t)q * DD + d] = cv;  // z + (z_q - z)
  const float diff = zv - cv;
  float sq = diff * diff;
#pragma unroll
  for (int off = 1; off < 64; off <<= 1) sq += __shfl_xor(sq, off, 64);
  if (d == 0) {
    out_idx[q] = (float)k;  // exact in f32 (k < 8192)
    atomicAdd(&cs[k], 1.0f);
    atomicAdd(&parts[blockIdx.x & 63], sq);
  }
  atomicAdd(&dw[(size_t)k * DD + d], zv);
}

__global__ __launch_bounds__(256) void k_newcs(
    const float* __restrict__ ema_cs, const float* __restrict__ cs,
    float* __restrict__ out_ncs, float* __restrict__ n_acc,
    const float* __restrict__ parts, float* __restrict__ sumsq_tot) {
  if (blockIdx.x == 0 && threadIdx.x < 64) {
    float sv = parts[threadIdx.x];
#pragma unroll
    for (int off = 1; off < 64; off <<= 1) sv += __shfl_xor(sv, off, 64);
    if (threadIdx.x == 0) *sumsq_tot = sv;
  }
  int k = blockIdx.x * 256 + threadIdx.x;
  float v = 0.99f * ema_cs[k] + 0.01f * cs[k];
  out_ncs[k] = v;
  float su = v;
#pragma unroll
  for (int off = 1; off < 64; off <<= 1) su += __shfl_xor(su, off, 64);
  __shared__ float ss[4];
  if ((threadIdx.x & 63) == 0) ss[threadIdx.x >> 6] = su;
  __syncthreads();
  if (threadIdx.x == 0) atomicAdd(n_acc, ss[0] + ss[1] + ss[2] + ss[3]);
}

__global__ __launch_bounds__(256) void k_finalout(
    const float* __restrict__ ema_ws, const float* __restrict__ dw,
    const float* __restrict__ ncs, const float* __restrict__ n_acc,
    const float* __restrict__ sumsq_tot, float* __restrict__ out_ncb,
    float* __restrict__ out_nws, float* __restrict__ out_loss) {
  int i = blockIdx.x * 256 + threadIdx.x;
  int k = i >> 6;
  float n = *n_acc;
  float v = ncs[k];
  float smoothed = (v + 1e-5f) / (n + (float)KC * 1e-5f) * n;
  float nws = 0.99f * ema_ws[i] + 0.01f * dw[i];
  out_nws[i] = nws;
  out_ncb[i] = nws / smoothed;
  if (i == 0) *out_loss = 1.25f * (*sumsq_tot) * (1.0f / 1048576.0f);
}

extern "C" void kernel_launch(void* const* d_in, const int* in_sizes, int n_in,
                              void* d_out, int out_size, void* d_ws,
                              size_t ws_size, hipStream_t stream) {
  const float* z = (const float*)d_in[0];
  const float* cb = (const float*)d_in[1];
  const float* ema_cs = (const float*)d_in[2];
  const float* ema_ws = (const float*)d_in[3];

  float* out = (float*)d_out;
  float* zq_out = out;              // 1048576
  float* loss_out = out + 1048576;  // 1
  float* idx_out = out + 1048577;   // 16384
  float* ncb_out = out + 1064961;   // 524288
  float* ncs_out = out + 1589249;   // 8192
  float* nws_out = out + 1597441;   // 524288

  float* ws = (float*)d_ws;
  float* dw = ws;                    // 524288
  float* cs = ws + 524288;           // 8192
  float* parts = ws + 532480;        // 64
  float* n_acc = ws + 532544;        // 1
  float* sumsq_tot = ws + 532545;    // 1
  float* cnorm = ws + 532608;        // 8192
  float* pmin = ws + 540800;         // 262144
  int* pidx = (int*)(ws + 802944);   // 262144

  // zero dw..sumsq_tot (contiguous prefix)
  hipMemsetAsync(d_ws, 0, (size_t)532546 * sizeof(float), stream);

  k_cnorm<<<KC / 256, 256, 0, stream>>>(cb, cnorm);
  k_argmin<<<dim3(NQ / 256, KSPLIT), 256, 0, stream>>>(z, cb, cnorm, pmin,
                                                       pidx);
  k_assign<<<NQ / 4, 256, 0, stream>>>(z, cb, pmin, pidx, zq_out, idx_out, dw,
                                       cs, parts);
  k_newcs<<<KC / 256, 256, 0, stream>>>(ema_cs, cs, ncs_out, n_acc, parts,
                                        sumsq_tot);
  k_finalout<<<KC * DD / 256, 256, 0, stream>>>(ema_ws, dw, ncs_out, n_acc,
                                                sumsq_tot, ncb_out, nws_out,
                                                loss_out);
}